// Round 1
// baseline (692.187 us; speedup 1.0000x reference)
//
#include <hip/hip_runtime.h>
#include <stdint.h>

// LightGCN on MI355X.
// Reference: deg = in-degree (segment_sum over col); dinv = rsqrt(deg) (0 if deg==0);
// per layer: x' = scatter_add_{col}( x[row] * dinv[row]*dinv[col] ); out = mean(x0,x1,x2,x3).
//
// Strategy: build destination-CSR once per call (no hot-loop atomics), then
// 3 pull-mode SpMV layers: one 64-lane wave per destination node, lane = feature dim.
// Edge metadata (src, norm) loaded coalesced 64-wide then broadcast via __shfl,
// so every x gather is a coalesced 256 B wave load (hits L2/L3 — all data < 256 MiB).

#define N_NODES 100000
#define N_EDGES 3200000
#define DIM 64

#define SCAN_BLOCK 256
#define SCAN_ITEMS 8
#define SCAN_CHUNK (SCAN_BLOCK * SCAN_ITEMS)  // 2048
#define SCAN_NBLOCKS ((N_NODES + SCAN_CHUNK - 1) / SCAN_CHUNK)  // 49

__global__ void k_count_deg(const int* __restrict__ col, int* __restrict__ deg) {
    int e = blockIdx.x * blockDim.x + threadIdx.x;
    if (e < N_EDGES) atomicAdd(&deg[col[e]], 1);
}

__global__ void k_dinv(const int* __restrict__ deg, float* __restrict__ dinv) {
    int i = blockIdx.x * blockDim.x + threadIdx.x;
    if (i < N_NODES) {
        int d = deg[i];
        dinv[i] = (d > 0) ? rsqrtf((float)d) : 0.0f;
    }
}

// Per-block exclusive scan of deg -> base; block totals -> bsums.
__global__ void k_scan1(const int* __restrict__ deg, int* __restrict__ base,
                        int* __restrict__ bsums) {
    int t = threadIdx.x;
    int blockStart = blockIdx.x * SCAN_CHUNK;
    int idx0 = blockStart + t * SCAN_ITEMS;

    int v[SCAN_ITEMS];
    int s = 0;
#pragma unroll
    for (int k = 0; k < SCAN_ITEMS; k++) {
        int idx = idx0 + k;
        v[k] = (idx < N_NODES) ? deg[idx] : 0;
        s += v[k];
    }

    int lane = t & 63;
    int waveId = t >> 6;
    // inclusive wave scan of per-thread sums
    int sum = s;
#pragma unroll
    for (int off = 1; off < 64; off <<= 1) {
        int u = __shfl_up(sum, off);
        if (lane >= off) sum += u;
    }
    int exclusive = sum - s;

    __shared__ int waveTotals[4];
    if (lane == 63) waveTotals[waveId] = sum;
    __syncthreads();
    int waveOff = 0;
    for (int w = 0; w < waveId; w++) waveOff += waveTotals[w];

    int run = exclusive + waveOff;
#pragma unroll
    for (int k = 0; k < SCAN_ITEMS; k++) {
        int idx = idx0 + k;
        if (idx < N_NODES) base[idx] = run;
        run += v[k];
    }
    if (t == SCAN_BLOCK - 1) bsums[blockIdx.x] = run;  // chunk total
}

// Exclusive scan of block sums (numBlocks <= 64), in place.
__global__ void k_scan2(int* __restrict__ bsums, int numBlocks) {
    int lane = threadIdx.x;
    int v = (lane < numBlocks) ? bsums[lane] : 0;
    int sum = v;
#pragma unroll
    for (int off = 1; off < 64; off <<= 1) {
        int u = __shfl_up(sum, off);
        if (lane >= off) sum += u;
    }
    if (lane < numBlocks) bsums[lane] = sum - v;
}

__global__ void k_scan3(int* __restrict__ base, const int* __restrict__ bsums) {
    int i = blockIdx.x * blockDim.x + threadIdx.x;
    if (i < N_NODES) base[i] += bsums[i / SCAN_CHUNK];
}

__global__ void k_fill(const int* __restrict__ ei, const float* __restrict__ dinv,
                       const int* __restrict__ base, int* __restrict__ cursor,
                       int* __restrict__ csrc, float* __restrict__ cnorm) {
    int e = blockIdx.x * blockDim.x + threadIdx.x;
    if (e >= N_EDGES) return;
    int r = ei[e];
    int c = ei[N_EDGES + e];
    int k = atomicAdd(&cursor[c], 1);
    int p = base[c] + k;
    csrc[p] = r;
    cnorm[p] = dinv[r] * dinv[c];
}

// One wave per destination node; lane = feature dim.
// mode 0: y = Ax;        acc = emb + y
// mode 1: y = Ax;        acc += y
// mode 2: (skip y)       acc = (acc + Ax) * 0.25
__global__ __launch_bounds__(256) void k_spmv(
    const int* __restrict__ base, const int* __restrict__ deg,
    const int* __restrict__ csrc, const float* __restrict__ cnorm,
    const float* __restrict__ x, float* __restrict__ y,
    const float* __restrict__ emb, float* __restrict__ acc, int mode) {
    int wave = (blockIdx.x * blockDim.x + threadIdx.x) >> 6;
    int lane = threadIdx.x & 63;
    if (wave >= N_NODES) return;

    int start = base[wave];
    int cnt = deg[wave];

    float a = 0.0f;
    int pos = 0;
    while (pos < cnt) {
        int take = min(64, cnt - pos);
        int s = 0;
        float nm = 0.0f;
        if (lane < take) {
            s = csrc[start + pos + lane];
            nm = cnorm[start + pos + lane];
        }
        int j = 0;
        for (; j + 4 <= take; j += 4) {
            int s0 = __shfl(s, j), s1 = __shfl(s, j + 1);
            int s2 = __shfl(s, j + 2), s3 = __shfl(s, j + 3);
            float n0 = __shfl(nm, j), n1 = __shfl(nm, j + 1);
            float n2 = __shfl(nm, j + 2), n3 = __shfl(nm, j + 3);
            float v0 = x[s0 * DIM + lane];
            float v1 = x[s1 * DIM + lane];
            float v2 = x[s2 * DIM + lane];
            float v3 = x[s3 * DIM + lane];
            a += v0 * n0;
            a += v1 * n1;
            a += v2 * n2;
            a += v3 * n3;
        }
        for (; j < take; j++) {
            int ss = __shfl(s, j);
            float nn = __shfl(nm, j);
            a += x[ss * DIM + lane] * nn;
        }
        pos += take;
    }

    int o = wave * DIM + lane;
    if (mode == 0) {
        y[o] = a;
        acc[o] = emb[o] + a;
    } else if (mode == 1) {
        y[o] = a;
        acc[o] += a;
    } else {
        acc[o] = (acc[o] + a) * 0.25f;
    }
}

extern "C" void kernel_launch(void* const* d_in, const int* in_sizes, int n_in,
                              void* d_out, int out_size, void* d_ws, size_t ws_size,
                              hipStream_t stream) {
    const float* emb = (const float*)d_in[0];
    const int* ei = (const int*)d_in[1];  // [2, E]: row = ei[0:E], col = ei[E:2E]
    float* out = (float*)d_out;

    char* ws = (char*)d_ws;
    size_t off = 0;
    auto alloc = [&](size_t bytes) -> void* {
        void* p = ws + off;
        off += (bytes + 511) & ~(size_t)511;
        return p;
    };
    int* deg = (int*)alloc((size_t)N_NODES * 4);
    float* dinv = (float*)alloc((size_t)N_NODES * 4);
    int* base = (int*)alloc((size_t)N_NODES * 4);
    int* cursor = (int*)alloc((size_t)N_NODES * 4);
    int* bsums = (int*)alloc(64 * 4);
    int* csrc = (int*)alloc((size_t)N_EDGES * 4);
    float* cnorm = (float*)alloc((size_t)N_EDGES * 4);
    float* xA = (float*)alloc((size_t)N_NODES * DIM * 4);
    float* xB = (float*)alloc((size_t)N_NODES * DIM * 4);

    hipMemsetAsync(deg, 0, (size_t)N_NODES * 4, stream);
    hipMemsetAsync(cursor, 0, (size_t)N_NODES * 4, stream);

    int eBlocks = (N_EDGES + 255) / 256;
    int nBlocks = (N_NODES + 255) / 256;

    k_count_deg<<<eBlocks, 256, 0, stream>>>(ei + N_EDGES, deg);
    k_dinv<<<nBlocks, 256, 0, stream>>>(deg, dinv);
    k_scan1<<<SCAN_NBLOCKS, SCAN_BLOCK, 0, stream>>>(deg, base, bsums);
    k_scan2<<<1, 64, 0, stream>>>(bsums, SCAN_NBLOCKS);
    k_scan3<<<nBlocks, 256, 0, stream>>>(base, bsums);
    k_fill<<<eBlocks, 256, 0, stream>>>(ei, dinv, base, cursor, csrc, cnorm);

    int spmvBlocks = (N_NODES + 3) / 4;  // 4 waves/block, 1 wave/node
    k_spmv<<<spmvBlocks, 256, 0, stream>>>(base, deg, csrc, cnorm, emb, xA, emb, out, 0);
    k_spmv<<<spmvBlocks, 256, 0, stream>>>(base, deg, csrc, cnorm, xA, xB, emb, out, 1);
    k_spmv<<<spmvBlocks, 256, 0, stream>>>(base, deg, csrc, cnorm, xB, xA, emb, out, 2);
}